// Round 22
// baseline (74.598 us; speedup 1.0000x reference)
//
#include <hip/hip_runtime.h>
#include <hip/hip_bf16.h>

typedef unsigned long long u64;
typedef unsigned int u32;
typedef __attribute__((ext_vector_type(4))) double f64x4;

#define NB   64
#define NPOS 1024
#define NOUT 25
#define NCLS 20
#define BIGCAP 256
#define ECAP   2048
#define TINY_TH (30.0f / 1024.0f)

// ---- workspace layout (bytes) ----
#define OFF_CNT   0          // int bigcnt[64] + int edgecnt[64] = 512
#define OFF_BIGL  512        // int biglist[64*256]  = 65536
#define OFF_EDGL  66048      // u32 edges[64*2048]   = 524288 -> end 590336

// ---------------- kernel 0: zero the 128 counters (1 block, ~2 us) -----------
__global__ __launch_bounds__(128) void k_zero(int* __restrict__ cnt)
{
    cnt[threadIdx.x] = 0;
}

// ---------------- f64 epilogue + big-box detection ---------------------------
__device__ __forceinline__ void epilogue(const double* __restrict__ acc,
                                         const float* __restrict__ bias,
                                         int b, int n,
                                         float* __restrict__ boxes_out,
                                         float* __restrict__ scores_out,
                                         float* __restrict__ cls_out,
                                         int* __restrict__ bigcnt,
                                         int* __restrict__ biglist)
{
    double p[NOUT];
#pragma unroll
    for (int o = 0; o < NOUT; ++o) p[o] = acc[o] + (double)bias[o];

    double conf = 1.0 / (1.0 + exp(-p[0]));
    double m = p[1]; int ci = 0;
#pragma unroll
    for (int i = 2; i <= NCLS; ++i) {
        if (p[i] > m) { m = p[i]; ci = i - 1; }
    }
    double ssum = 0.0;
#pragma unroll
    for (int i = 0; i < NCLS; ++i) ssum += exp(p[1 + i] - m);
    double best = conf / ssum;

    int gx = n & 31, gy = n >> 5;
    double sx = 1.0 / (1.0 + exp(-p[21]));
    double sy = 1.0 / (1.0 + exp(-p[22]));
    double cx = (sx + (double)gx) * 32.0;
    double cy = (sy + (double)gy) * 32.0;
    double bw = exp(p[23]), bh = exp(p[24]);
    double x1 = (cx - bw * 0.5) * (1.0 / 1024.0);
    double y1 = (cy - bh * 0.5) * (1.0 / 1024.0);
    double x2 = (cx + bw * 0.5) * (1.0 / 1024.0);
    double y2 = (cy + bh * 0.5) * (1.0 / 1024.0);
    x1 = fmin(fmax(x1, 0.0), 1.0); y1 = fmin(fmax(y1, 0.0), 1.0);
    x2 = fmin(fmax(x2, 0.0), 1.0); y2 = fmin(fmax(y2, 0.0), 1.0);

    float fx1 = (float)x1, fy1 = (float)y1, fx2 = (float)x2, fy2 = (float)y2;
    int gi = b * NPOS + n;
    ((float4*)boxes_out)[gi] = make_float4(fx1, fy1, fx2, fy2);
    scores_out[gi] = (float)best;
    cls_out[gi]    = (float)ci;

    if (!((fx2 - fx1 < TINY_TH) && (fy2 - fy1 < TINY_TH))) {
        int s = atomicAdd(&bigcnt[b], 1);
        if (s < BIGCAP) biglist[b * BIGCAP + s] = n;
    }
}

// ---------------- guarded transposed B load from original w [25][512] --------
__device__ __forceinline__ float4 loadB(const float* __restrict__ w, int c, int bo4)
{
    float4 r = make_float4(0.f, 0.f, 0.f, 0.f);
    int o = bo4 * 4;
    if (o + 0 < NOUT) r.x = w[(o + 0) * 512 + c];
    if (o + 1 < NOUT) r.y = w[(o + 1) * 512 + c];
    if (o + 2 < NOUT) r.z = w[(o + 2) * 512 + c];
    if (o + 3 < NOUT) r.w = w[(o + 3) * 512 + c];
    return r;
}

// ---------------- kernel 1: f64 MFMA GEMM, f32-B LDS, self-staged B ----------
__global__ __launch_bounds__(256, 6) void k_main(const float* __restrict__ feat,
                                                 const float* __restrict__ w,
                                                 const float* __restrict__ bias,
                                                 float* __restrict__ boxes_out,
                                                 float* __restrict__ scores_out,
                                                 float* __restrict__ cls_out,
                                                 int* __restrict__ bigcnt,
                                                 int* __restrict__ biglist)
{
    __shared__ __align__(16) char smem[24576];
    float* AbF = (float*)smem;                     // [2][32ch*64pos] f32 = 16384 B
    float* BbF = (float*)(smem + 16384);           // [2][32ch*32out] f32 = 8192 B
    double (*pd)[33] = (double(*)[33])smem;        // [64][33] f64, post-loop reuse

    const int b   = blockIdx.y;
    const int tid = threadIdx.x;
    const int l   = tid & 63;
    const int wv  = tid >> 6;
    const int pg  = wv >> 1;          // position half (32 pos)
    const int oh  = wv & 1;           // out half (16 outs)
    const int n0  = blockIdx.x * 64;

    // --- runtime D-row calibration: A[m][0]=m, B[0][n]=1 => D[m][n]=m -------
    double ca = ((l >> 4) == 0) ? (double)(l & 15) : 0.0;
    double cb = ((l >> 4) == 0) ? 1.0 : 0.0;
    f64x4 cd = {0.0, 0.0, 0.0, 0.0};
    cd = __builtin_amdgcn_mfma_f64_16x16x4f64(ca, cb, cd, 0, 0, 0);
    int rmap[4];
#pragma unroll
    for (int v = 0; v < 4; ++v) {
        int r = (int)(cd[v] + 0.5);
        rmap[v] = (r < 0) ? 0 : (r > 15 ? 15 : r);
    }

    const float* __restrict__ featb = feat + (size_t)b * 512 * NPOS + n0;
    const int bch = tid >> 3, bo4 = tid & 7;   // B staging: channel, out-quad

#define A_SRC(C0, IT) (((const float4*)(featb + (size_t)((C0) + wv*8 + (IT)*4 + (l>>4)) * NPOS)) + (l & 15))
#define A_DST(BUF, IT) ((float4*)(AbF + (BUF)*2048 + (wv*8 + (IT)*4) * 64 + l*4))
#define B_DST(BUF) ((float4*)(BbF + (BUF)*1024 + bch*32 + bo4*4))

    f64x4 acc0 = {0.0, 0.0, 0.0, 0.0};   // pos frag 0 (pg*32+0..15) x out-half
    f64x4 acc1 = {0.0, 0.0, 0.0, 0.0};   // pos frag 1 (pg*32+16..31)

    // prologue: stage chunk 0
    float4 ra0 = *A_SRC(0, 0), ra1 = *A_SRC(0, 1);
    float4 rb  = loadB(w, bch, bo4);
    *A_DST(0, 0) = ra0;  *A_DST(0, 1) = ra1;
    *B_DST(0) = rb;
    __syncthreads();

#pragma unroll 1
    for (int t = 0; t < 16; ++t) {
        const int buf = t & 1;
        const bool more = (t + 1) < 16;
        const int c1 = (t + 1) * 32;
        if (more) {                       // issue next-chunk loads (hide under MFMA)
            ra0 = *A_SRC(c1, 0);  ra1 = *A_SRC(c1, 1);
            rb  = loadB(w, c1 + bch, bo4);
        }
#pragma unroll
        for (int s = 0; s < 8; ++s) {     // 8 k-steps x 4 ch
            const int rowA = buf*2048 + (4*s + (l >> 4)) * 64 + pg * 32 + (l & 15);
            const int rowB = buf*1024 + (4*s + (l >> 4)) * 32 + oh * 16 + (l & 15);
            double av0 = (double)AbF[rowA];
            double av1 = (double)AbF[rowA + 16];
            double bv  = (double)BbF[rowB];
            acc0 = __builtin_amdgcn_mfma_f64_16x16x4f64(av0, bv, acc0, 0, 0, 0);
            acc1 = __builtin_amdgcn_mfma_f64_16x16x4f64(av1, bv, acc1, 0, 0, 0);
        }
        if (more) {                       // write next chunk into alt buffer
            *A_DST(buf ^ 1, 0) = ra0;  *A_DST(buf ^ 1, 1) = ra1;
            *B_DST(buf ^ 1) = rb;
        }
        __syncthreads();
    }
#undef A_SRC
#undef A_DST
#undef B_DST

    // dump D to LDS as [pos][out] with calibrated row map (smem reused)
#pragma unroll
    for (int v = 0; v < 4; ++v) {
        int r0 = pg * 32 + rmap[v];
        pd[r0][oh * 16 + (l & 15)]      = acc0[v];
        pd[r0 + 16][oh * 16 + (l & 15)] = acc1[v];
    }
    __syncthreads();

    if (tid < 64) {
        double acc[NOUT];
#pragma unroll
        for (int o = 0; o < NOUT; ++o) acc[o] = pd[tid][o];
        int n = n0 + tid;
        epilogue(acc, bias, b, n, boxes_out, scores_out, cls_out, bigcnt, biglist);
    }
}

// ---------------- pair IoU check + edge emit ---------------------------------
__device__ __forceinline__ void pair_check(int b, int p, int i,
                                           float4 bp, float ap, int cp,
                                           const float4* __restrict__ boxes4,
                                           const float* __restrict__ scores,
                                           const float* __restrict__ cls,
                                           int* __restrict__ edgecnt,
                                           u32* __restrict__ edges,
                                           bool need_tiny_i)
{
    float si = scores[b * NPOS + i];
    if (si <= 0.01f) return;
    float4 bi = boxes4[b * NPOS + i];
    if (need_tiny_i) {
        if (!((bi.z - bi.x < TINY_TH) && (bi.w - bi.y < TINY_TH))) return;
    }
    if ((int)cls[b * NPOS + i] != cp) return;
    float xx1 = fmaxf(bi.x, bp.x), yy1 = fmaxf(bi.y, bp.y);
    float xx2 = fminf(bi.z, bp.z), yy2 = fminf(bi.w, bp.w);
    float ww = fmaxf(1e-28f, xx2 - xx1);
    float hh = fmaxf(1e-28f, yy2 - yy1);
    float inter = ww * hh;
    float ai = (bi.z - bi.x) * (bi.w - bi.y);
    float uni = ai + ap - inter;
    if (uni > 0.0f && inter > 0.5f * uni) {
        int u = p < i ? p : i, v = p < i ? i : p;
        int slot = atomicAdd(&edgecnt[b], 1);
        if (slot < ECAP) edges[(size_t)b * ECAP + slot] = ((u32)u << 16) | (u32)v;
    }
}

// ---------------- kernel 2: suppression-edge discovery -----------------------
__global__ __launch_bounds__(256) void k_edge(const float4* __restrict__ boxes4,
                                              const float* __restrict__ scores,
                                              const float* __restrict__ cls,
                                              const int* __restrict__ bigcnt,
                                              const int* __restrict__ biglist,
                                              int* __restrict__ edgecnt,
                                              u32* __restrict__ edges)
{
    const int b = blockIdx.y;
    const int p = blockIdx.x * 256 + threadIdx.x;
    const float sp = scores[b * NPOS + p];
    if (sp <= 0.01f) return;
    const float4 bp = boxes4[b * NPOS + p];
    const float ap = (bp.z - bp.x) * (bp.w - bp.y);
    const int cp = (int)cls[b * NPOS + p];
    const bool tinyp = (bp.z - bp.x < TINY_TH) && (bp.w - bp.y < TINY_TH);
    const int gx = p & 31, gy = p >> 5;

    if (tinyp) {    // 4 canonical (i<p) neighbors, both-tiny pairs
        if (gy > 0 && gx > 0)  pair_check(b, p, p - 33, bp, ap, cp, boxes4, scores, cls, edgecnt, edges, true);
        if (gy > 0)            pair_check(b, p, p - 32, bp, ap, cp, boxes4, scores, cls, edgecnt, edges, true);
        if (gy > 0 && gx < 31) pair_check(b, p, p - 31, bp, ap, cp, boxes4, scores, cls, edgecnt, edges, true);
        if (gx > 0)            pair_check(b, p, p - 1,  bp, ap, cp, boxes4, scores, cls, edgecnt, edges, true);
    }
    int nb = bigcnt[b]; if (nb > BIGCAP) nb = BIGCAP;
    for (int t = 0; t < nb; ++t) {
        int q = biglist[b * BIGCAP + t];
        if (q == p) continue;
        if (!tinyp && p > q) continue;            // big-big: canonical p<q
        pair_check(b, p, q, bp, ap, cp, boxes4, scores, cls, edgecnt, edges, false);
    }
}

// ---------------- kernel 3: sequential NMS on the edge list ------------------
__global__ __launch_bounds__(64) void k_resolve(const float* __restrict__ scores,
                                                const int* __restrict__ edgecnt,
                                                const u32* __restrict__ edges,
                                                float* __restrict__ keep_out)
{
    __shared__ u64 keepw[16];
    __shared__ u64 done[ECAP / 64];
    const int b = blockIdx.x, lane = threadIdx.x;

    for (int t = 0; t < 16; ++t) {
        bool v = scores[b * NPOS + t * 64 + lane] > 0.01f;
        u64 w = __ballot(v);
        if (lane == 0) keepw[t] = w;
    }
    if (lane < ECAP / 64) done[lane] = 0ull;
    __syncthreads();

    int E = edgecnt[b]; if (E > ECAP) E = ECAP;
    if (lane == 0 && E > 0) {
        const u32* eb = edges + (size_t)b * ECAP;
        for (int it = 0; it < E; ++it) {
            int bestj = -1, bidx = 0, bsup = 0, btgt = 0;
            float bs = -1.0f;
            for (int j = 0; j < E; ++j) {
                if ((done[j >> 6] >> (j & 63)) & 1ull) continue;
                u32 e = eb[j];
                int u = (int)(e >> 16), v = (int)(e & 0xffffu);
                float su = scores[b * NPOS + u], sv = scores[b * NPOS + v];
                int sup, tgt; float ss;
                if (su > sv || (su == sv && u < v)) { sup = u; tgt = v; ss = su; }
                else                                { sup = v; tgt = u; ss = sv; }
                if (bestj < 0 || ss > bs || (ss == bs && sup < bidx)) {
                    bestj = j; bs = ss; bidx = sup; bsup = sup; btgt = tgt;
                }
            }
            done[bestj >> 6] |= 1ull << (bestj & 63);
            if ((keepw[bsup >> 6] >> (bsup & 63)) & 1ull)
                keepw[btgt >> 6] &= ~(1ull << (btgt & 63));
        }
    }
    __syncthreads();

    for (int t = 0; t < 16; ++t) {
        u64 w = keepw[t];
        keep_out[b * NPOS + t * 64 + lane] = ((w >> lane) & 1ull) ? 1.0f : 0.0f;
    }
}

// ------------------------------------------------------------------------------
extern "C" void kernel_launch(void* const* d_in, const int* in_sizes, int n_in,
                              void* d_out, int out_size, void* d_ws, size_t ws_size,
                              hipStream_t stream)
{
    const float* feat = (const float*)d_in[0];
    const float* w    = (const float*)d_in[1];
    const float* bias = (const float*)d_in[2];

    float* out = (float*)d_out;
    float* boxes_out  = out;
    float* scores_out = out + NB * NPOS * 4;
    float* cls_out    = out + NB * NPOS * 5;
    float* keep_out   = out + NB * NPOS * 6;

    char* ws = (char*)d_ws;
    int*    bigcnt = (int*)   (ws + OFF_CNT);
    int*    edgecnt= (int*)   (ws + OFF_CNT + 256);
    int*    biglist= (int*)   (ws + OFF_BIGL);
    u32*    edges  = (u32*)   (ws + OFF_EDGL);

    hipLaunchKernelGGL(k_zero,   dim3(1),      dim3(128), 0, stream, (int*)(ws + OFF_CNT));
    hipLaunchKernelGGL(k_main,   dim3(16, 64), dim3(256), 0, stream, feat, w, bias,
                       boxes_out, scores_out, cls_out, bigcnt, biglist);
    hipLaunchKernelGGL(k_edge,   dim3(4, 64),  dim3(256), 0, stream,
                       (const float4*)boxes_out, scores_out, cls_out,
                       bigcnt, biglist, edgecnt, edges);
    hipLaunchKernelGGL(k_resolve, dim3(64),    dim3(64),  0, stream, scores_out,
                       edgecnt, edges, keep_out);
}

// Round 23
// 70.121 us; speedup vs baseline: 1.0638x; 1.0638x over previous
//
#include <hip/hip_runtime.h>
#include <hip/hip_bf16.h>

typedef unsigned long long u64;
typedef unsigned int u32;
typedef __attribute__((ext_vector_type(4))) double f64x4;

#define NB   64
#define NPOS 1024
#define NOUT 25
#define NCLS 20
#define ECAP_B 512            // edges per k_edge block
#define ECAP_S 2048           // total per batch (4 blocks)
#define TINY_TH (30.0f / 1024.0f)

// ---- workspace layout (bytes); all buffers written-before-read each call ----
#define OFF_BIGC  0           // int bigcntT[64*16]       = 4096
#define OFF_BIGL  4096        // int biglistT[64*16*64]   = 262144
#define OFF_EDGC  266240      // int edgecntT[64*4]       = 1024
#define OFF_EDGL  267264      // u32 edgesT[64*4*512]     = 524288 -> end 791552

// ---------------- f64 epilogue -----------------------------------------------
__device__ __forceinline__ void epilogue(const double* __restrict__ acc,
                                         const float* __restrict__ bias,
                                         int b, int n, bool* isbig,
                                         float* __restrict__ boxes_out,
                                         float* __restrict__ scores_out,
                                         float* __restrict__ cls_out)
{
    double p[NOUT];
#pragma unroll
    for (int o = 0; o < NOUT; ++o) p[o] = acc[o] + (double)bias[o];

    double conf = 1.0 / (1.0 + exp(-p[0]));
    double m = p[1]; int ci = 0;
#pragma unroll
    for (int i = 2; i <= NCLS; ++i) {
        if (p[i] > m) { m = p[i]; ci = i - 1; }
    }
    double ssum = 0.0;
#pragma unroll
    for (int i = 0; i < NCLS; ++i) ssum += exp(p[1 + i] - m);
    double best = conf / ssum;

    int gx = n & 31, gy = n >> 5;
    double sx = 1.0 / (1.0 + exp(-p[21]));
    double sy = 1.0 / (1.0 + exp(-p[22]));
    double cx = (sx + (double)gx) * 32.0;
    double cy = (sy + (double)gy) * 32.0;
    double bw = exp(p[23]), bh = exp(p[24]);
    double x1 = (cx - bw * 0.5) * (1.0 / 1024.0);
    double y1 = (cy - bh * 0.5) * (1.0 / 1024.0);
    double x2 = (cx + bw * 0.5) * (1.0 / 1024.0);
    double y2 = (cy + bh * 0.5) * (1.0 / 1024.0);
    x1 = fmin(fmax(x1, 0.0), 1.0); y1 = fmin(fmax(y1, 0.0), 1.0);
    x2 = fmin(fmax(x2, 0.0), 1.0); y2 = fmin(fmax(y2, 0.0), 1.0);

    float fx1 = (float)x1, fy1 = (float)y1, fx2 = (float)x2, fy2 = (float)y2;
    int gi = b * NPOS + n;
    ((float4*)boxes_out)[gi] = make_float4(fx1, fy1, fx2, fy2);
    scores_out[gi] = (float)best;
    cls_out[gi]    = (float)ci;
    *isbig = !((fx2 - fx1 < TINY_TH) && (fy2 - fy1 < TINY_TH));
}

// ---------------- kernel 1: f64 MFMA GEMM, coalesced self-staged B -----------
// R20 structure; B staged per-chunk straight from w with coalesced o-passes
// into pad-33 LDS. Per-tile big-lists via ballot (unconditional stores -> no
// counter zeroing anywhere). LDS 24832 B -> 6 blocks/CU.
__global__ __launch_bounds__(256, 6) void k_main(const float* __restrict__ feat,
                                                 const float* __restrict__ w,
                                                 const float* __restrict__ bias,
                                                 float* __restrict__ boxes_out,
                                                 float* __restrict__ scores_out,
                                                 float* __restrict__ cls_out,
                                                 int* __restrict__ bigcntT,
                                                 int* __restrict__ biglistT)
{
    __shared__ __align__(16) char smem[24832];
    float* AbF = (float*)smem;                     // [2][32ch*64pos] = 16384 B
    float* BbF = (float*)(smem + 16384);           // [2][32ch*33]    = 8448 B
    double (*pd)[33] = (double(*)[33])smem;        // [64][33] f64, post-loop reuse

    const int b   = blockIdx.y;
    const int tx  = blockIdx.x;
    const int tid = threadIdx.x;
    const int l   = tid & 63;
    const int wv  = tid >> 6;
    const int pg  = wv >> 1;          // position half (32 pos)
    const int oh  = wv & 1;           // out half (16 outs)
    const int n0  = tx * 64;

    // --- runtime D-row calibration: A[m][0]=m, B[0][n]=1 => D[m][n]=m -------
    double ca = ((l >> 4) == 0) ? (double)(l & 15) : 0.0;
    double cb = ((l >> 4) == 0) ? 1.0 : 0.0;
    f64x4 cd = {0.0, 0.0, 0.0, 0.0};
    cd = __builtin_amdgcn_mfma_f64_16x16x4f64(ca, cb, cd, 0, 0, 0);
    int rmap[4];
#pragma unroll
    for (int v = 0; v < 4; ++v) {
        int r = (int)(cd[v] + 0.5);
        rmap[v] = (r < 0) ? 0 : (r > 15 ? 15 : r);
    }

    const float* __restrict__ featb = feat + (size_t)b * 512 * NPOS + n0;
    const int bo = tid >> 5;          // o-group base within pass
    const int bc = tid & 31;          // channel within chunk

#define A_SRC(C0, IT) (((const float4*)(featb + (size_t)((C0) + wv*8 + (IT)*4 + (l>>4)) * NPOS)) + (l & 15))
#define A_DST(BUF, IT) ((float4*)(AbF + (BUF)*2048 + (wv*8 + (IT)*4) * 64 + l*4))
    // B: pass p loads o = p*8+bo, channel c0+bc (coalesced); pad-33 write
#define B_LOAD(C0, P, DST) do {                                               \
    int o_ = (P)*8 + bo;                                                      \
    (DST) = (o_ < NOUT) ? w[(size_t)o_ * 512 + (C0) + bc] : 0.0f;             \
} while (0)
#define B_WRITE(BUF, P, V) (BbF[(BUF)*1056 + bc*33 + (P)*8 + bo] = (V))

    f64x4 acc0 = {0.0, 0.0, 0.0, 0.0};   // pos frag 0 (pg*32+0..15) x out-half
    f64x4 acc1 = {0.0, 0.0, 0.0, 0.0};   // pos frag 1 (pg*32+16..31)

    // prologue: stage chunk 0
    float4 ra0 = *A_SRC(0, 0), ra1 = *A_SRC(0, 1);
    float rb0, rb1, rb2, rb3;
    B_LOAD(0, 0, rb0); B_LOAD(0, 1, rb1); B_LOAD(0, 2, rb2); B_LOAD(0, 3, rb3);
    *A_DST(0, 0) = ra0;  *A_DST(0, 1) = ra1;
    B_WRITE(0, 0, rb0); B_WRITE(0, 1, rb1); B_WRITE(0, 2, rb2); B_WRITE(0, 3, rb3);
    __syncthreads();

#pragma unroll 1
    for (int t = 0; t < 16; ++t) {
        const int buf = t & 1;
        const bool more = (t + 1) < 16;
        const int c1 = (t + 1) * 32;
        if (more) {                       // issue next-chunk loads (hide under MFMA)
            ra0 = *A_SRC(c1, 0);  ra1 = *A_SRC(c1, 1);
            B_LOAD(c1, 0, rb0); B_LOAD(c1, 1, rb1);
            B_LOAD(c1, 2, rb2); B_LOAD(c1, 3, rb3);
        }
#pragma unroll
        for (int s = 0; s < 8; ++s) {     // 8 k-steps x 4 ch
            const int rowA = buf*2048 + (4*s + (l >> 4)) * 64 + pg * 32 + (l & 15);
            const int rowB = buf*1056 + (4*s + (l >> 4)) * 33 + oh * 16 + (l & 15);
            double av0 = (double)AbF[rowA];
            double av1 = (double)AbF[rowA + 16];
            double bv  = (double)BbF[rowB];
            acc0 = __builtin_amdgcn_mfma_f64_16x16x4f64(av0, bv, acc0, 0, 0, 0);
            acc1 = __builtin_amdgcn_mfma_f64_16x16x4f64(av1, bv, acc1, 0, 0, 0);
        }
        if (more) {                       // write next chunk into alt buffer
            *A_DST(buf ^ 1, 0) = ra0;  *A_DST(buf ^ 1, 1) = ra1;
            B_WRITE(buf ^ 1, 0, rb0); B_WRITE(buf ^ 1, 1, rb1);
            B_WRITE(buf ^ 1, 2, rb2); B_WRITE(buf ^ 1, 3, rb3);
        }
        __syncthreads();
    }
#undef A_SRC
#undef A_DST
#undef B_LOAD
#undef B_WRITE

    // dump D to LDS as [pos][out] with calibrated row map (smem reused)
#pragma unroll
    for (int v = 0; v < 4; ++v) {
        int r0 = pg * 32 + rmap[v];
        pd[r0][oh * 16 + (l & 15)]      = acc0[v];
        pd[r0 + 16][oh * 16 + (l & 15)] = acc1[v];
    }
    __syncthreads();

    if (tid < 64) {                       // wave 0, all 64 lanes
        double acc[NOUT];
#pragma unroll
        for (int o = 0; o < NOUT; ++o) acc[o] = pd[tid][o];
        int n = n0 + tid;
        bool isbig;
        epilogue(acc, bias, b, n, &isbig, boxes_out, scores_out, cls_out);

        // per-tile big list via ballot compaction (unconditional count store)
        u64 mask = __ballot(isbig);
        if (isbig) {
            int slot = __popcll(mask & ((1ull << tid) - 1ull));
            biglistT[(b * 16 + tx) * 64 + slot] = n;
        }
        if (tid == 0) bigcntT[b * 16 + tx] = (int)__popcll(mask);
    }
}

// ---------------- kernel 2: suppression-edge discovery (block-local lists) ---
__global__ __launch_bounds__(256) void k_edge(const float4* __restrict__ boxes4,
                                              const float* __restrict__ scores,
                                              const float* __restrict__ cls,
                                              const int* __restrict__ bigcntT,
                                              const int* __restrict__ biglistT,
                                              int* __restrict__ edgecntT,
                                              u32* __restrict__ edgesT)
{
    __shared__ int bl[NPOS];              // gathered big list (worst case 1024)
    __shared__ int nbtot;
    __shared__ u32 eds[ECAP_B];
    __shared__ int ecnt;
    const int b  = blockIdx.y;
    const int bx = blockIdx.x;
    const int tid = threadIdx.x;
    const int p = bx * 256 + tid;

    if (tid == 0) {
        int s = 0;
        for (int t = 0; t < 16; ++t) {
            int c = bigcntT[b * 16 + t];
            for (int k = 0; k < c; ++k) bl[s++] = biglistT[(b * 16 + t) * 64 + k];
        }
        nbtot = s;
        ecnt = 0;
    }
    __syncthreads();

    const float sp = scores[b * NPOS + p];
    if (sp > 0.01f) {
        const float4 bp = boxes4[b * NPOS + p];
        const float ap = (bp.z - bp.x) * (bp.w - bp.y);
        const int cp = (int)cls[b * NPOS + p];
        const bool tinyp = (bp.z - bp.x < TINY_TH) && (bp.w - bp.y < TINY_TH);
        const int gx = p & 31, gy = p >> 5;

#define PAIR(I, NEEDTINY) do {                                                \
    int i_ = (I);                                                             \
    if (scores[b * NPOS + i_] > 0.01f) {                                      \
        float4 bi = boxes4[b * NPOS + i_];                                    \
        bool ok = true;                                                       \
        if (NEEDTINY)                                                         \
            ok = (bi.z - bi.x < TINY_TH) && (bi.w - bi.y < TINY_TH);          \
        if (ok && (int)cls[b * NPOS + i_] == cp) {                            \
            float xx1 = fmaxf(bi.x, bp.x), yy1 = fmaxf(bi.y, bp.y);           \
            float xx2 = fminf(bi.z, bp.z), yy2 = fminf(bi.w, bp.w);           \
            float ww = fmaxf(1e-28f, xx2 - xx1);                              \
            float hh = fmaxf(1e-28f, yy2 - yy1);                              \
            float inter = ww * hh;                                            \
            float ai = (bi.z - bi.x) * (bi.w - bi.y);                         \
            float uni = ai + ap - inter;                                      \
            if (uni > 0.0f && inter > 0.5f * uni) {                           \
                int u_ = p < i_ ? p : i_, v_ = p < i_ ? i_ : p;               \
                int slot = atomicAdd(&ecnt, 1);                               \
                if (slot < ECAP_B) eds[slot] = ((u32)u_ << 16) | (u32)v_;     \
            }                                                                 \
        }                                                                     \
    }                                                                         \
} while (0)

        if (tinyp) {   // 4 canonical (i<p) neighbors, both-tiny pairs
            if (gy > 0 && gx > 0)  PAIR(p - 33, true);
            if (gy > 0)            PAIR(p - 32, true);
            if (gy > 0 && gx < 31) PAIR(p - 31, true);
            if (gx > 0)            PAIR(p - 1,  true);
        }
        int nb = nbtot;
        for (int t = 0; t < nb; ++t) {
            int q = bl[t];
            if (q == p) continue;
            if (!tinyp && p > q) continue;       // big-big: canonical p<q
            PAIR(q, false);
        }
#undef PAIR
    }
    __syncthreads();

    int E = ecnt; if (E > ECAP_B) E = ECAP_B;
    if (tid == 0) edgecntT[b * 4 + bx] = E;      // unconditional store
    for (int i = tid; i < E; i += 256)
        edgesT[(size_t)(b * 4 + bx) * ECAP_B + i] = eds[i];
}

// ---------------- kernel 3: sequential NMS on the gathered edge list ---------
__global__ __launch_bounds__(64) void k_resolve(const float* __restrict__ scores,
                                                const int* __restrict__ edgecntT,
                                                const u32* __restrict__ edgesT,
                                                float* __restrict__ keep_out)
{
    __shared__ u64 keepw[16];
    __shared__ u32 eds[ECAP_S];
    __shared__ u64 done[ECAP_S / 64];
    __shared__ int Esh;
    const int b = blockIdx.x, lane = threadIdx.x;

    for (int t = 0; t < 16; ++t) {
        bool v = scores[b * NPOS + t * 64 + lane] > 0.01f;
        u64 w = __ballot(v);
        if (lane == 0) keepw[t] = w;
    }
    if (lane < ECAP_S / 64) done[lane] = 0ull;
    if (lane == 0) {                      // gather 4 sub-lists
        int off = 0;
        for (int e = 0; e < 4; ++e) {
            int c = edgecntT[b * 4 + e];
            if (c > ECAP_B) c = ECAP_B;
            for (int j = 0; j < c; ++j)
                eds[off++] = edgesT[(size_t)(b * 4 + e) * ECAP_B + j];
        }
        Esh = off;
    }
    __syncthreads();

    int E = Esh;
    if (lane == 0 && E > 0) {
        for (int it = 0; it < E; ++it) {
            int bestj = -1, bidx = 0, bsup = 0, btgt = 0;
            float bs = -1.0f;
            for (int j = 0; j < E; ++j) {
                if ((done[j >> 6] >> (j & 63)) & 1ull) continue;
                u32 e = eds[j];
                int u = (int)(e >> 16), v = (int)(e & 0xffffu);
                float su = scores[b * NPOS + u], sv = scores[b * NPOS + v];
                int sup, tgt; float ss;
                if (su > sv || (su == sv && u < v)) { sup = u; tgt = v; ss = su; }
                else                                { sup = v; tgt = u; ss = sv; }
                if (bestj < 0 || ss > bs || (ss == bs && sup < bidx)) {
                    bestj = j; bs = ss; bidx = sup; bsup = sup; btgt = tgt;
                }
            }
            done[bestj >> 6] |= 1ull << (bestj & 63);
            if ((keepw[bsup >> 6] >> (bsup & 63)) & 1ull)
                keepw[btgt >> 6] &= ~(1ull << (btgt & 63));
        }
    }
    __syncthreads();

    for (int t = 0; t < 16; ++t) {
        u64 w = keepw[t];
        keep_out[b * NPOS + t * 64 + lane] = ((w >> lane) & 1ull) ? 1.0f : 0.0f;
    }
}

// ------------------------------------------------------------------------------
extern "C" void kernel_launch(void* const* d_in, const int* in_sizes, int n_in,
                              void* d_out, int out_size, void* d_ws, size_t ws_size,
                              hipStream_t stream)
{
    const float* feat = (const float*)d_in[0];
    const float* w    = (const float*)d_in[1];
    const float* bias = (const float*)d_in[2];

    float* out = (float*)d_out;
    float* boxes_out  = out;
    float* scores_out = out + NB * NPOS * 4;
    float* cls_out    = out + NB * NPOS * 5;
    float* keep_out   = out + NB * NPOS * 6;

    char* ws = (char*)d_ws;
    int* bigcntT  = (int*)(ws + OFF_BIGC);
    int* biglistT = (int*)(ws + OFF_BIGL);
    int* edgecntT = (int*)(ws + OFF_EDGC);
    u32* edgesT   = (u32*)(ws + OFF_EDGL);

    hipLaunchKernelGGL(k_main,   dim3(16, 64), dim3(256), 0, stream, feat, w, bias,
                       boxes_out, scores_out, cls_out, bigcntT, biglistT);
    hipLaunchKernelGGL(k_edge,   dim3(4, 64),  dim3(256), 0, stream,
                       (const float4*)boxes_out, scores_out, cls_out,
                       bigcntT, biglistT, edgecntT, edgesT);
    hipLaunchKernelGGL(k_resolve, dim3(64),    dim3(64),  0, stream, scores_out,
                       edgecntT, edgesT, keep_out);
}